// Round 13
// baseline (288.021 us; speedup 1.0000x reference)
//
#include <hip/hip_runtime.h>
#include <hip/hip_bf16.h>

#define Bb  2
#define Tt  2048
#define Cc  1024
#define Hh  16
#define KVH 4
#define HD  64

typedef __attribute__((ext_vector_type(4))) float  f32x4;
typedef __attribute__((ext_vector_type(8))) __bf16 bf16x8;

typedef __attribute__((address_space(1))) const unsigned int glob_u32;
typedef __attribute__((address_space(3))) unsigned int       lds_u32;

__device__ __forceinline__ void gload16(const void* g, void* l) {
  __builtin_amdgcn_global_load_lds((glob_u32*)g, (lds_u32*)l, 16, 0, 0);
}

__device__ __forceinline__ unsigned short f2bf_bits(float f) {
  unsigned int u = __builtin_bit_cast(unsigned int, f);
  u = (u + 0x7fff + ((u >> 16) & 1)) >> 16;
  return (unsigned short)u;
}

// ---------------- cast x f32 -> bf16 ----------------
__global__ __launch_bounds__(256) void cast_x_kernel(const float* __restrict__ in,
                                                     unsigned short* __restrict__ out, int n) {
  int i = (blockIdx.x * 256 + threadIdx.x) * 4;
  if (i >= n) return;
  float4 f = *(const float4*)(in + i);
  unsigned long long v = (unsigned long long)f2bf_bits(f.x)
                       | ((unsigned long long)f2bf_bits(f.y) << 16)
                       | ((unsigned long long)f2bf_bits(f.z) << 32)
                       | ((unsigned long long)f2bf_bits(f.w) << 48);
  *(unsigned long long*)(out + i) = v;
}

// ---------------- transpose + cast: W [K][N] f32 -> Wt [N][K] bf16 ----------------
__global__ __launch_bounds__(256) void transpose_cast(const float* __restrict__ W,
                                                      unsigned short* __restrict__ Wt,
                                                      int K, int N) {
  __shared__ float tile[32][33];
  int k0 = blockIdx.x * 32, n0 = blockIdx.y * 32;
  int tx = threadIdx.x;
  for (int i = threadIdx.y; i < 32; i += 8)
    tile[i][tx] = W[(size_t)(k0 + i) * N + n0 + tx];
  __syncthreads();
  for (int i = threadIdx.y; i < 32; i += 8)
    Wt[(size_t)(n0 + i) * K + k0 + tx] = f2bf_bits(tile[tx][i]);
}

// ---------------- GEMM: A[M][K]bf16 * Bt[N][K]bf16 -> C[M][ldc]f32 (m97-style 128x128) ----------------
__global__ __launch_bounds__(256) void gemm_bf16(const unsigned short* __restrict__ A,
                                                 const unsigned short* __restrict__ Bt,
                                                 float* __restrict__ C,
                                                 int M, int N, int K, int ldc) {
  __shared__ unsigned short As[128 * 32];
  __shared__ unsigned short Bs[128 * 32];
  const int tid = threadIdx.x;
  const int wave = tid >> 6, lane = tid & 63;
  const int row0 = blockIdx.x * 128;
  const int col0 = blockIdx.y * 128;
  const int wm = (wave >> 1) * 64, wn = (wave & 1) * 64;
  f32x4 acc[4][4];
#pragma unroll
  for (int m = 0; m < 4; ++m)
#pragma unroll
    for (int n = 0; n < 4; ++n) acc[m][n] = (f32x4){0.f, 0.f, 0.f, 0.f};

  for (int k0 = 0; k0 < K; k0 += 32) {
#pragma unroll
    for (int c = 0; c < 2; ++c) {
      int chunk = wave * 2 + c;
      int r = chunk * 16 + (lane >> 2);
      int kc = (lane & 3) * 8;
      gload16(A + (size_t)(row0 + r) * K + k0 + kc, (void*)(As + chunk * 512));
      gload16(Bt + (size_t)(col0 + r) * K + k0 + kc, (void*)(Bs + chunk * 512));
    }
    __syncthreads();
    bf16x8 af[4], bfr[4];
#pragma unroll
    for (int m = 0; m < 4; ++m)
      af[m] = *(const bf16x8*)&As[(wm + m * 16 + (lane & 15)) * 32 + (lane >> 4) * 8];
#pragma unroll
    for (int n = 0; n < 4; ++n)
      bfr[n] = *(const bf16x8*)&Bs[(wn + n * 16 + (lane & 15)) * 32 + (lane >> 4) * 8];
#pragma unroll
    for (int m = 0; m < 4; ++m)
#pragma unroll
      for (int n = 0; n < 4; ++n)
        acc[m][n] = __builtin_amdgcn_mfma_f32_16x16x32_bf16(af[m], bfr[n], acc[m][n], 0, 0, 0);
    __syncthreads();
  }
#pragma unroll
  for (int m = 0; m < 4; ++m)
#pragma unroll
    for (int n = 0; n < 4; ++n) {
      int col = col0 + wn + n * 16 + (lane & 15);
      int rbase = row0 + wm + m * 16 + (lane >> 4) * 4;
#pragma unroll
      for (int i = 0; i < 4; ++i)
        C[(size_t)(rbase + i) * ldc + col] = acc[m][n][i];
    }
}

// ---------------- RoPE + RMSNorm + relayout (Q,K only) ----------------
__global__ __launch_bounds__(256) void rope_rms_kernel(const float* __restrict__ QKV,
                                                       const float* __restrict__ cosT,
                                                       const float* __restrict__ sinT,
                                                       unsigned short* __restrict__ Qb,
                                                       unsigned short* __restrict__ Kb) {
  int wid = blockIdx.x * 4 + (threadIdx.x >> 6);
  int lane = threadIdx.x & 63;
  int slot = wid % 20;
  int bt = wid / 20;
  int b = bt >> 11;        // / T
  int t = bt & 2047;
  const float* base = QKV + (size_t)bt * 1536;
  bool isQ = slot < 16;
  int hh = isQ ? slot : (slot - 16);
  float v = base[(isQ ? hh * 64 : 1024 + hh * 64) + lane];
  float other = __shfl_xor(v, 32);
  int d = lane & 31;
  float c = cosT[t * 32 + d], sn = sinT[t * 32 + d];
  // first half: x1*c + x2*s ; second half: -x1*s + x2*c
  float o = (lane < 32) ? (v * c + other * sn) : (v * c - other * sn);
  float ss = o * o;
  ss += __shfl_xor(ss, 1);  ss += __shfl_xor(ss, 2);
  ss += __shfl_xor(ss, 4);  ss += __shfl_xor(ss, 8);
  ss += __shfl_xor(ss, 16); ss += __shfl_xor(ss, 32);
  float scale = rsqrtf(ss * (1.f / 64.f) + 1e-6f);
  if (isQ) scale *= 0.125f;  // fold 1/sqrt(HD) into Q
  unsigned short ob = f2bf_bits(o * scale);
  if (isQ) Qb[((size_t)(b * Hh + hh) * Tt + t) * 64 + lane] = ob;
  else     Kb[((size_t)(b * KVH + hh) * Tt + t) * 64 + lane] = ob;
}

// ---------------- V transpose: QKV[.,1280+vh*64+d] f32 -> Vt[b][kvh][d][t] bf16 ----------------
__global__ __launch_bounds__(256) void v_transpose(const float* __restrict__ QKV,
                                                   unsigned short* __restrict__ Vt) {
  __shared__ float tile[64][65];
  const int tid = threadIdx.x;
  const int bid = blockIdx.x;          // [B*KVH*32]
  const int ttile = bid & 31;
  const int head = bid >> 5;           // b*KVH + vh
  const int b = head >> 2, vh = head & 3;
  const int t0 = ttile * 64;
  const int tx = tid & 63, ty = tid >> 6;
  const size_t inbase = ((size_t)(b * Tt + t0)) * 1536 + 1280 + vh * 64;
  for (int i = ty; i < 64; i += 4)        // i = t_local, tx = d  (coalesced read)
    tile[i][tx] = QKV[inbase + (size_t)i * 1536 + tx];
  __syncthreads();
  const size_t outbase = (size_t)head * 64 * 2048 + t0;
  for (int i = ty; i < 64; i += 4)        // i = d, tx = t_local (coalesced write)
    Vt[outbase + (size_t)i * 2048 + tx] = f2bf_bits(tile[tx][i]);
}

// ---------------- flash attention: 4 waves/block, paired Q-tiles for causal load balance ----------------
// Block (bh, p) processes Q-tiles p and 31-p sequentially: (p+1)+(32-p) = 33 KV-tile iters for
// every block -> uniform per-CU work (was 4..128 block-iters per CU; occupancy 19%).
// K tile: [kv][d] rows of 128B ; V tile: V^T [d][kv] rows of 128B -> both b128-readable.
__global__ __launch_bounds__(256) void attn_kernel(const unsigned short* __restrict__ Qb,
                                                   const unsigned short* __restrict__ Kb,
                                                   const unsigned short* __restrict__ Vt,
                                                   unsigned short* __restrict__ Yb) {
  __shared__ unsigned short Ks[2][64 * 64];
  __shared__ unsigned short Vs[2][64 * 64];
  __shared__ unsigned short Ps[4 * 16 * 64];
  const int tid = threadIdx.x, wave = tid >> 6, lane = tid & 63;
  const int bid = blockIdx.x;
  const int pp = bid & 15;             // tile-pair index
  const int bh = bid >> 4;
  const int b = bh >> 4, h = bh & 15;
  const int kvh = h >> 2;
  const size_t qbase = (size_t)(b * Hh + h) * Tt * 64;
  const size_t kbase = (size_t)(b * KVH + kvh) * Tt * 64;
  const size_t vbase = (size_t)(b * KVH + kvh) * 64 * 2048;

  // staging geometry (shared by K and V^T tiles: 64 rows x 128 B)
  const int chunk0 = wave * 2;
  const int sr0 = chunk0 * 8 + (lane >> 3);
  const int sr1 = sr0 + 8;
  const int sb0 = ((lane & 7) * 16) ^ ((sr0 & 7) << 4);   // pre-swizzled byte col
  const int sb1 = ((lane & 7) * 16) ^ ((sr1 & 7) << 4);

  char* PsW = (char*)Ps + wave * 2048;

  for (int pass = 0; pass < 2; ++pass) {
    const int qtile = pass ? (31 - pp) : pp;
    const int q0 = qtile * 64;

    bf16x8 qf[2];
    {
      int qrow = q0 + wave * 16 + (lane & 15);
      const unsigned short* qp = Qb + qbase + (size_t)qrow * 64 + (lane >> 4) * 8;
      qf[0] = *(const bf16x8*)qp;
      qf[1] = *(const bf16x8*)(qp + 32);
    }
    f32x4 acc[4];
    float m_r[4], l_r[4];
#pragma unroll
    for (int n = 0; n < 4; ++n) acc[n] = (f32x4){0.f, 0.f, 0.f, 0.f};
#pragma unroll
    for (int i = 0; i < 4; ++i) { m_r[i] = -INFINITY; l_r[i] = 0.f; }

    if (pass) __syncthreads();  // all waves done reading LDS of previous pass before restaging

    // prologue: stage tile 0 into buffer 0
    gload16(Kb + kbase + (size_t)sr0 * 64 + (sb0 >> 1), (void*)(Ks[0] + chunk0 * 512));
    gload16(Vt + vbase + (size_t)sr0 * 2048 + (sb0 >> 1), (void*)(Vs[0] + chunk0 * 512));
    gload16(Kb + kbase + (size_t)sr1 * 64 + (sb1 >> 1), (void*)(Ks[0] + chunk0 * 512 + 512));
    gload16(Vt + vbase + (size_t)sr1 * 2048 + (sb1 >> 1), (void*)(Vs[0] + chunk0 * 512 + 512));

    const int ntiles = qtile + 1;
    for (int t = 0; t < ntiles; ++t) {
      const int cur = t & 1;
      __syncthreads();   // drains stage(t) [vmcnt(0) before s_barrier]; all waves done with buf cur^1
      if (t + 1 < ntiles) {
        const int nxt = cur ^ 1;
        const size_t kt = kbase + (size_t)(t + 1) * 64 * 64;   // K tile t+1: row offset (t+1)*64, 64 elem/row
        const size_t vt = vbase + (size_t)(t + 1) * 64;        // V^T tile t+1: col offset (t+1)*64, 2048 elem/row
        gload16(Kb + kt + (size_t)sr0 * 64 + (sb0 >> 1), (void*)(Ks[nxt] + chunk0 * 512));
        gload16(Vt + vt + (size_t)sr0 * 2048 + (sb0 >> 1), (void*)(Vs[nxt] + chunk0 * 512));
        gload16(Kb + kt + (size_t)sr1 * 64 + (sb1 >> 1), (void*)(Ks[nxt] + chunk0 * 512 + 512));
        gload16(Vt + vt + (size_t)sr1 * 2048 + (sb1 >> 1), (void*)(Vs[nxt] + chunk0 * 512 + 512));
      }
      // S = Q K^T  (Q pre-scaled by 0.125)
      f32x4 s[4];
#pragma unroll
      for (int n = 0; n < 4; ++n) {
        f32x4 z = (f32x4){0.f, 0.f, 0.f, 0.f};
#pragma unroll
        for (int st = 0; st < 2; ++st) {
          int krow = n * 16 + (lane & 15);
          int kb = ((lane >> 4) * 16 + st * 64) ^ ((krow & 7) << 4);
          bf16x8 kf = *(const bf16x8*)((const char*)Ks[cur] + krow * 128 + kb);
          z = __builtin_amdgcn_mfma_f32_16x16x32_bf16(qf[st], kf, z, 0, 0, 0);
        }
        s[n] = z;
      }
      if (t == qtile) {
#pragma unroll
        for (int n = 0; n < 4; ++n)
#pragma unroll
          for (int i = 0; i < 4; ++i) {
            int kcol = t * 64 + n * 16 + (lane & 15);
            int qrow = q0 + wave * 16 + (lane >> 4) * 4 + i;
            if (kcol > qrow) s[n][i] = -INFINITY;
          }
      }
      // online softmax (rows spread over 16-lane groups)
#pragma unroll
      for (int i = 0; i < 4; ++i) {
        float rmax = fmaxf(fmaxf(s[0][i], s[1][i]), fmaxf(s[2][i], s[3][i]));
        rmax = fmaxf(rmax, __shfl_xor(rmax, 1));
        rmax = fmaxf(rmax, __shfl_xor(rmax, 2));
        rmax = fmaxf(rmax, __shfl_xor(rmax, 4));
        rmax = fmaxf(rmax, __shfl_xor(rmax, 8));
        float mn = fmaxf(m_r[i], rmax);
        float corr = __expf(m_r[i] - mn);
        m_r[i] = mn;
        float rsum = 0.f;
        int prow = (lane >> 4) * 4 + i;
#pragma unroll
        for (int n = 0; n < 4; ++n) {
          float pv = __expf(s[n][i] - mn);
          rsum += pv;
          int cb = ((n * 16 + (lane & 15)) * 2) ^ ((prow & 7) << 4);
          *(__bf16*)(PsW + prow * 128 + cb) = (__bf16)pv;
        }
        rsum += __shfl_xor(rsum, 1);
        rsum += __shfl_xor(rsum, 2);
        rsum += __shfl_xor(rsum, 4);
        rsum += __shfl_xor(rsum, 8);
        l_r[i] = l_r[i] * corr + rsum;
#pragma unroll
        for (int n = 0; n < 4; ++n) acc[n][i] *= corr;
      }
      asm volatile("s_waitcnt lgkmcnt(0)" ::: "memory");  // Ps ds_writes visible to own wave's reads
      // O += P V : A = P (b128), B = V^T rows (b128)
      {
        int prow = lane & 15;
        bf16x8 pf0 = *(const bf16x8*)((const char*)PsW + prow * 128 + (((lane >> 4) * 16 + 0)  ^ ((prow & 7) << 4)));
        bf16x8 pf1 = *(const bf16x8*)((const char*)PsW + prow * 128 + (((lane >> 4) * 16 + 64) ^ ((prow & 7) << 4)));
#pragma unroll
        for (int n = 0; n < 4; ++n) {
          int d = n * 16 + (lane & 15);
          bf16x8 vf0 = *(const bf16x8*)((const char*)Vs[cur] + d * 128 + (((lane >> 4) * 16 + 0)  ^ ((d & 7) << 4)));
          bf16x8 vf1 = *(const bf16x8*)((const char*)Vs[cur] + d * 128 + (((lane >> 4) * 16 + 64) ^ ((d & 7) << 4)));
          acc[n] = __builtin_amdgcn_mfma_f32_16x16x32_bf16(pf0, vf0, acc[n], 0, 0, 0);
          acc[n] = __builtin_amdgcn_mfma_f32_16x16x32_bf16(pf1, vf1, acc[n], 0, 0, 0);
        }
      }
    }
    // epilogue: divide by softmax denom, write y[b][t][h*64+d]
#pragma unroll
    for (int n = 0; n < 4; ++n)
#pragma unroll
      for (int i = 0; i < 4; ++i) {
        int qrow = q0 + wave * 16 + (lane >> 4) * 4 + i;
        int col = h * 64 + n * 16 + (lane & 15);
        float v = acc[n][i] / l_r[i];
        *(__bf16*)(Yb + (size_t)(b * Tt + qrow) * 1024 + col) = (__bf16)v;
      }
  }
}

extern "C" void kernel_launch(void* const* d_in, const int* in_sizes, int n_in,
                              void* d_out, int out_size, void* d_ws, size_t ws_size,
                              hipStream_t stream) {
  const float* x    = (const float*)d_in[0];
  const float* cosT = (const float*)d_in[1];
  const float* sinT = (const float*)d_in[2];
  const float* Wq   = (const float*)d_in[3];
  const float* Wk   = (const float*)d_in[4];
  const float* Wv   = (const float*)d_in[5];
  const float* Wo   = (const float*)d_in[6];
  float* out = (float*)d_out;
  char* ws = (char*)d_ws;

  unsigned short* xb    = (unsigned short*)(ws);                 //  8,388,608 B
  unsigned short* Wqkvt = (unsigned short*)(ws + 8388608);       //  3,145,728 B  [1536][1024]
  unsigned short* Wot   = (unsigned short*)(ws + 11534336);      //  2,097,152 B  [1024][1024]
  float*          QKV   = (float*)(ws + 13631488);               // 25,165,824 B  [4096][1536]
  unsigned short* Qb    = (unsigned short*)(ws + 38797312);      //  8,388,608 B
  unsigned short* Kb    = (unsigned short*)(ws + 47185920);      //  2,097,152 B
  unsigned short* Vt    = (unsigned short*)(ws + 49283072);      //  2,097,152 B  [B][KVH][64][2048]
  unsigned short* Yb    = (unsigned short*)(ws + 51380224);      //  8,388,608 B

  cast_x_kernel<<<4096, 256, 0, stream>>>(x, xb, Bb * Tt * Cc);
  transpose_cast<<<dim3(32, 32), dim3(32, 8), 0, stream>>>(Wq, Wqkvt, 1024, 1024);
  transpose_cast<<<dim3(32, 8),  dim3(32, 8), 0, stream>>>(Wk, Wqkvt + 1024 * 1024, 1024, 256);
  transpose_cast<<<dim3(32, 8),  dim3(32, 8), 0, stream>>>(Wv, Wqkvt + 1280 * 1024, 1024, 256);
  transpose_cast<<<dim3(32, 32), dim3(32, 8), 0, stream>>>(Wo, Wot, 1024, 1024);

  gemm_bf16<<<dim3(32, 12), 256, 0, stream>>>(xb, Wqkvt, QKV, 4096, 1536, 1024, 1536);
  rope_rms_kernel<<<20480, 256, 0, stream>>>(QKV, cosT, sinT, Qb, Kb);
  v_transpose<<<256, 256, 0, stream>>>(QKV, Vt);
  attn_kernel<<<1024, 256, 0, stream>>>(Qb, Kb, Vt, Yb);   // 64 bh x 16 tile-pairs
  gemm_bf16<<<dim3(32, 8), 256, 0, stream>>>(Yb, Wot, out, 4096, 1024, 1024, 1024);
}

// Round 15
// 246.661 us; speedup vs baseline: 1.1677x; 1.1677x over previous
//
#include <hip/hip_runtime.h>
#include <hip/hip_bf16.h>

#define Bb  2
#define Tt  2048
#define Cc  1024
#define Hh  16
#define KVH 4
#define HD  64

typedef __attribute__((ext_vector_type(4))) float  f32x4;
typedef __attribute__((ext_vector_type(8))) __bf16 bf16x8;

typedef __attribute__((address_space(1))) const unsigned int glob_u32;
typedef __attribute__((address_space(3))) unsigned int       lds_u32;

__device__ __forceinline__ void gload16(const void* g, void* l) {
  __builtin_amdgcn_global_load_lds((glob_u32*)g, (lds_u32*)l, 16, 0, 0);
}

__device__ __forceinline__ unsigned short f2bf_bits(float f) {
  unsigned int u = __builtin_bit_cast(unsigned int, f);
  u = (u + 0x7fff + ((u >> 16) & 1)) >> 16;
  return (unsigned short)u;
}

// ---------------- cast x f32 -> bf16 ----------------
__global__ __launch_bounds__(256) void cast_x_kernel(const float* __restrict__ in,
                                                     unsigned short* __restrict__ out, int n) {
  int i = (blockIdx.x * 256 + threadIdx.x) * 4;
  if (i >= n) return;
  float4 f = *(const float4*)(in + i);
  unsigned long long v = (unsigned long long)f2bf_bits(f.x)
                       | ((unsigned long long)f2bf_bits(f.y) << 16)
                       | ((unsigned long long)f2bf_bits(f.z) << 32)
                       | ((unsigned long long)f2bf_bits(f.w) << 48);
  *(unsigned long long*)(out + i) = v;
}

// ---------------- transpose + cast: W [K][N] f32 -> Wt [N][K] bf16 ----------------
__global__ __launch_bounds__(256) void transpose_cast(const float* __restrict__ W,
                                                      unsigned short* __restrict__ Wt,
                                                      int K, int N) {
  __shared__ float tile[32][33];
  int k0 = blockIdx.x * 32, n0 = blockIdx.y * 32;
  int tx = threadIdx.x;
  for (int i = threadIdx.y; i < 32; i += 8)
    tile[i][tx] = W[(size_t)(k0 + i) * N + n0 + tx];
  __syncthreads();
  for (int i = threadIdx.y; i < 32; i += 8)
    Wt[(size_t)(n0 + i) * K + k0 + tx] = f2bf_bits(tile[tx][i]);
}

// ---------------- GEMM: A[M][K]bf16 * Bt[N][K]bf16 -> C[M][ldc]f32 (m97-style 128x128) ----------------
__global__ __launch_bounds__(256) void gemm_bf16(const unsigned short* __restrict__ A,
                                                 const unsigned short* __restrict__ Bt,
                                                 float* __restrict__ C,
                                                 int M, int N, int K, int ldc) {
  __shared__ unsigned short As[128 * 32];
  __shared__ unsigned short Bs[128 * 32];
  const int tid = threadIdx.x;
  const int wave = tid >> 6, lane = tid & 63;
  const int row0 = blockIdx.x * 128;
  const int col0 = blockIdx.y * 128;
  const int wm = (wave >> 1) * 64, wn = (wave & 1) * 64;
  f32x4 acc[4][4];
#pragma unroll
  for (int m = 0; m < 4; ++m)
#pragma unroll
    for (int n = 0; n < 4; ++n) acc[m][n] = (f32x4){0.f, 0.f, 0.f, 0.f};

  for (int k0 = 0; k0 < K; k0 += 32) {
#pragma unroll
    for (int c = 0; c < 2; ++c) {
      int chunk = wave * 2 + c;
      int r = chunk * 16 + (lane >> 2);
      int kc = (lane & 3) * 8;
      gload16(A + (size_t)(row0 + r) * K + k0 + kc, (void*)(As + chunk * 512));
      gload16(Bt + (size_t)(col0 + r) * K + k0 + kc, (void*)(Bs + chunk * 512));
    }
    __syncthreads();
    bf16x8 af[4], bfr[4];
#pragma unroll
    for (int m = 0; m < 4; ++m)
      af[m] = *(const bf16x8*)&As[(wm + m * 16 + (lane & 15)) * 32 + (lane >> 4) * 8];
#pragma unroll
    for (int n = 0; n < 4; ++n)
      bfr[n] = *(const bf16x8*)&Bs[(wn + n * 16 + (lane & 15)) * 32 + (lane >> 4) * 8];
#pragma unroll
    for (int m = 0; m < 4; ++m)
#pragma unroll
      for (int n = 0; n < 4; ++n)
        acc[m][n] = __builtin_amdgcn_mfma_f32_16x16x32_bf16(af[m], bfr[n], acc[m][n], 0, 0, 0);
    __syncthreads();
  }
#pragma unroll
  for (int m = 0; m < 4; ++m)
#pragma unroll
    for (int n = 0; n < 4; ++n) {
      int col = col0 + wn + n * 16 + (lane & 15);
      int rbase = row0 + wm + m * 16 + (lane >> 4) * 4;
#pragma unroll
      for (int i = 0; i < 4; ++i)
        C[(size_t)(rbase + i) * ldc + col] = acc[m][n][i];
    }
}

// ---------------- RoPE + RMSNorm + relayout (Q,K only) ----------------
__global__ __launch_bounds__(256) void rope_rms_kernel(const float* __restrict__ QKV,
                                                       const float* __restrict__ cosT,
                                                       const float* __restrict__ sinT,
                                                       unsigned short* __restrict__ Qb,
                                                       unsigned short* __restrict__ Kb) {
  int wid = blockIdx.x * 4 + (threadIdx.x >> 6);
  int lane = threadIdx.x & 63;
  int slot = wid % 20;
  int bt = wid / 20;
  int b = bt >> 11;        // / T
  int t = bt & 2047;
  const float* base = QKV + (size_t)bt * 1536;
  bool isQ = slot < 16;
  int hh = isQ ? slot : (slot - 16);
  float v = base[(isQ ? hh * 64 : 1024 + hh * 64) + lane];
  float other = __shfl_xor(v, 32);
  int d = lane & 31;
  float c = cosT[t * 32 + d], sn = sinT[t * 32 + d];
  // first half: x1*c + x2*s ; second half: -x1*s + x2*c
  float o = (lane < 32) ? (v * c + other * sn) : (v * c - other * sn);
  float ss = o * o;
  ss += __shfl_xor(ss, 1);  ss += __shfl_xor(ss, 2);
  ss += __shfl_xor(ss, 4);  ss += __shfl_xor(ss, 8);
  ss += __shfl_xor(ss, 16); ss += __shfl_xor(ss, 32);
  float scale = rsqrtf(ss * (1.f / 64.f) + 1e-6f);
  if (isQ) scale *= 0.125f;  // fold 1/sqrt(HD) into Q
  unsigned short ob = f2bf_bits(o * scale);
  if (isQ) Qb[((size_t)(b * Hh + hh) * Tt + t) * 64 + lane] = ob;
  else     Kb[((size_t)(b * KVH + hh) * Tt + t) * 64 + lane] = ob;
}

// ---------------- V transpose: QKV[.,1280+vh*64+d] f32 -> Vt[b][kvh][d][t] bf16 ----------------
__global__ __launch_bounds__(256) void v_transpose(const float* __restrict__ QKV,
                                                   unsigned short* __restrict__ Vt) {
  __shared__ float tile[64][65];
  const int tid = threadIdx.x;
  const int bid = blockIdx.x;          // [B*KVH*32]
  const int ttile = bid & 31;
  const int head = bid >> 5;           // b*KVH + vh
  const int b = head >> 2, vh = head & 3;
  const int t0 = ttile * 64;
  const int tx = tid & 63, ty = tid >> 6;
  const size_t inbase = ((size_t)(b * Tt + t0)) * 1536 + 1280 + vh * 64;
  for (int i = ty; i < 64; i += 4)        // i = t_local, tx = d  (coalesced read)
    tile[i][tx] = QKV[inbase + (size_t)i * 1536 + tx];
  __syncthreads();
  const size_t outbase = (size_t)head * 64 * 2048 + t0;
  for (int i = ty; i < 64; i += 4)        // i = d, tx = t_local (coalesced write)
    Vt[outbase + (size_t)i * 2048 + tx] = f2bf_bits(tile[tx][i]);
}

// ---------------- flash attention: 4 waves/block, 64 Q rows, 64-KV tiles ----------------
// r10 dispatch restored (pairing regressed: 112->141 us, full-chip clock droop).
// No-max softmax: RMSNorm'd Q,K with 1/8 folded into Q bound |S| <= 8 (Cauchy-Schwarz),
// so exp(S) in [3.4e-4, 2981] needs no max subtraction -> drops 4 shfl-max chains,
// corr exps, and the 16 acc-rescale mults per iteration.
// K tile: [kv][d] rows of 128B ; V tile: V^T [d][kv] rows of 128B -> both b128-readable.
__global__ __launch_bounds__(256) void attn_kernel(const unsigned short* __restrict__ Qb,
                                                   const unsigned short* __restrict__ Kb,
                                                   const unsigned short* __restrict__ Vt,
                                                   unsigned short* __restrict__ Yb) {
  __shared__ unsigned short Ks[2][64 * 64];
  __shared__ unsigned short Vs[2][64 * 64];
  __shared__ unsigned short Ps[4 * 16 * 64];
  const int tid = threadIdx.x, wave = tid >> 6, lane = tid & 63;
  const int bid = blockIdx.x;
  const int qtile = 31 - (bid & 31);   // big tiles first
  const int bh = bid >> 5;
  const int b = bh >> 4, h = bh & 15;
  const int kvh = h >> 2;
  const int q0 = qtile * 64;
  const size_t qbase = (size_t)(b * Hh + h) * Tt * 64;
  const size_t kbase = (size_t)(b * KVH + kvh) * Tt * 64;
  const size_t vbase = (size_t)(b * KVH + kvh) * 64 * 2048;

  // staging geometry (shared by K and V^T tiles: 64 rows x 128 B)
  const int chunk0 = wave * 2;
  const int sr0 = chunk0 * 8 + (lane >> 3);
  const int sr1 = sr0 + 8;
  const int sb0 = ((lane & 7) * 16) ^ ((sr0 & 7) << 4);   // pre-swizzled byte col
  const int sb1 = ((lane & 7) * 16) ^ ((sr1 & 7) << 4);

  bf16x8 qf[2];
  {
    int qrow = q0 + wave * 16 + (lane & 15);
    const unsigned short* qp = Qb + qbase + (size_t)qrow * 64 + (lane >> 4) * 8;
    qf[0] = *(const bf16x8*)qp;
    qf[1] = *(const bf16x8*)(qp + 32);
  }
  f32x4 acc[4];
  float l_r[4];
#pragma unroll
  for (int n = 0; n < 4; ++n) acc[n] = (f32x4){0.f, 0.f, 0.f, 0.f};
#pragma unroll
  for (int i = 0; i < 4; ++i) l_r[i] = 0.f;

  char* PsW = (char*)Ps + wave * 2048;

  const int ntiles = qtile + 1;
  // prologue: stage tile 0 into buffer 0
  {
    gload16(Kb + kbase + (size_t)sr0 * 64 + (sb0 >> 1), (void*)(Ks[0] + chunk0 * 512));
    gload16(Vt + vbase + (size_t)sr0 * 2048 + (sb0 >> 1), (void*)(Vs[0] + chunk0 * 512));
    gload16(Kb + kbase + (size_t)sr1 * 64 + (sb1 >> 1), (void*)(Ks[0] + chunk0 * 512 + 512));
    gload16(Vt + vbase + (size_t)sr1 * 2048 + (sb1 >> 1), (void*)(Vs[0] + chunk0 * 512 + 512));
  }

  for (int t = 0; t < ntiles; ++t) {
    const int cur = t & 1;
    __syncthreads();   // drains stage(t) [vmcnt(0) before s_barrier]; all waves done with buf cur^1
    if (t + 1 < ntiles) {
      const int nxt = cur ^ 1;
      const size_t kt = kbase + (size_t)(t + 1) * 64 * 64;   // K tile t+1: row offset (t+1)*64, 64 elem/row
      const size_t vt = vbase + (size_t)(t + 1) * 64;        // V^T tile t+1: col offset (t+1)*64, 2048 elem/row
      gload16(Kb + kt + (size_t)sr0 * 64 + (sb0 >> 1), (void*)(Ks[nxt] + chunk0 * 512));
      gload16(Vt + vt + (size_t)sr0 * 2048 + (sb0 >> 1), (void*)(Vs[nxt] + chunk0 * 512));
      gload16(Kb + kt + (size_t)sr1 * 64 + (sb1 >> 1), (void*)(Ks[nxt] + chunk0 * 512 + 512));
      gload16(Vt + vt + (size_t)sr1 * 2048 + (sb1 >> 1), (void*)(Vs[nxt] + chunk0 * 512 + 512));
    }
    // S = Q K^T  (Q pre-scaled by 0.125)
    f32x4 s[4];
#pragma unroll
    for (int n = 0; n < 4; ++n) {
      f32x4 z = (f32x4){0.f, 0.f, 0.f, 0.f};
#pragma unroll
      for (int st = 0; st < 2; ++st) {
        int krow = n * 16 + (lane & 15);
        int kb = ((lane >> 4) * 16 + st * 64) ^ ((krow & 7) << 4);
        bf16x8 kf = *(const bf16x8*)((const char*)Ks[cur] + krow * 128 + kb);
        z = __builtin_amdgcn_mfma_f32_16x16x32_bf16(qf[st], kf, z, 0, 0, 0);
      }
      s[n] = z;
    }
    if (t == qtile) {
#pragma unroll
      for (int n = 0; n < 4; ++n)
#pragma unroll
        for (int i = 0; i < 4; ++i) {
          int kcol = t * 64 + n * 16 + (lane & 15);
          int qrow = q0 + wave * 16 + (lane >> 4) * 4 + i;
          if (kcol > qrow) s[n][i] = -INFINITY;
        }
    }
    // no-max softmax: P = exp(S) directly (|S| <= 8 by qk-norm); masked -> exp(-inf) = 0
#pragma unroll
    for (int i = 0; i < 4; ++i) {
      float rsum = 0.f;
      int prow = (lane >> 4) * 4 + i;
#pragma unroll
      for (int n = 0; n < 4; ++n) {
        float pv = __expf(s[n][i]);
        rsum += pv;
        int cb = ((n * 16 + (lane & 15)) * 2) ^ ((prow & 7) << 4);
        *(__bf16*)(PsW + prow * 128 + cb) = (__bf16)pv;
      }
      rsum += __shfl_xor(rsum, 1);
      rsum += __shfl_xor(rsum, 2);
      rsum += __shfl_xor(rsum, 4);
      rsum += __shfl_xor(rsum, 8);
      l_r[i] += rsum;
    }
    asm volatile("s_waitcnt lgkmcnt(0)" ::: "memory");  // Ps ds_writes visible to own wave's reads
    // O += P V : A = P (b128), B = V^T rows (b128)
    {
      int prow = lane & 15;
      bf16x8 pf0 = *(const bf16x8*)((const char*)PsW + prow * 128 + (((lane >> 4) * 16 + 0)  ^ ((prow & 7) << 4)));
      bf16x8 pf1 = *(const bf16x8*)((const char*)PsW + prow * 128 + (((lane >> 4) * 16 + 64) ^ ((prow & 7) << 4)));
#pragma unroll
      for (int n = 0; n < 4; ++n) {
        int d = n * 16 + (lane & 15);
        bf16x8 vf0 = *(const bf16x8*)((const char*)Vs[cur] + d * 128 + (((lane >> 4) * 16 + 0)  ^ ((d & 7) << 4)));
        bf16x8 vf1 = *(const bf16x8*)((const char*)Vs[cur] + d * 128 + (((lane >> 4) * 16 + 64) ^ ((d & 7) << 4)));
        acc[n] = __builtin_amdgcn_mfma_f32_16x16x32_bf16(pf0, vf0, acc[n], 0, 0, 0);
        acc[n] = __builtin_amdgcn_mfma_f32_16x16x32_bf16(pf1, vf1, acc[n], 0, 0, 0);
      }
    }
  }
  // epilogue: divide by softmax denom, write y[b][t][h*64+d]
#pragma unroll
  for (int n = 0; n < 4; ++n)
#pragma unroll
    for (int i = 0; i < 4; ++i) {
      int qrow = q0 + wave * 16 + (lane >> 4) * 4 + i;
      int col = h * 64 + n * 16 + (lane & 15);
      float v = acc[n][i] / l_r[i];
      *(__bf16*)(Yb + (size_t)(b * Tt + qrow) * 1024 + col) = (__bf16)v;
    }
}

extern "C" void kernel_launch(void* const* d_in, const int* in_sizes, int n_in,
                              void* d_out, int out_size, void* d_ws, size_t ws_size,
                              hipStream_t stream) {
  const float* x    = (const float*)d_in[0];
  const float* cosT = (const float*)d_in[1];
  const float* sinT = (const float*)d_in[2];
  const float* Wq   = (const float*)d_in[3];
  const float* Wk   = (const float*)d_in[4];
  const float* Wv   = (const float*)d_in[5];
  const float* Wo   = (const float*)d_in[6];
  float* out = (float*)d_out;
  char* ws = (char*)d_ws;

  unsigned short* xb    = (unsigned short*)(ws);                 //  8,388,608 B
  unsigned short* Wqkvt = (unsigned short*)(ws + 8388608);       //  3,145,728 B  [1536][1024]
  unsigned short* Wot   = (unsigned short*)(ws + 11534336);      //  2,097,152 B  [1024][1024]
  float*          QKV   = (float*)(ws + 13631488);               // 25,165,824 B  [4096][1536]
  unsigned short* Qb    = (unsigned short*)(ws + 38797312);      //  8,388,608 B
  unsigned short* Kb    = (unsigned short*)(ws + 47185920);      //  2,097,152 B
  unsigned short* Vt    = (unsigned short*)(ws + 49283072);      //  2,097,152 B  [B][KVH][64][2048]
  unsigned short* Yb    = (unsigned short*)(ws + 51380224);      //  8,388,608 B

  cast_x_kernel<<<4096, 256, 0, stream>>>(x, xb, Bb * Tt * Cc);
  transpose_cast<<<dim3(32, 32), dim3(32, 8), 0, stream>>>(Wq, Wqkvt, 1024, 1024);
  transpose_cast<<<dim3(32, 8),  dim3(32, 8), 0, stream>>>(Wk, Wqkvt + 1024 * 1024, 1024, 256);
  transpose_cast<<<dim3(32, 8),  dim3(32, 8), 0, stream>>>(Wv, Wqkvt + 1280 * 1024, 1024, 256);
  transpose_cast<<<dim3(32, 32), dim3(32, 8), 0, stream>>>(Wo, Wot, 1024, 1024);

  gemm_bf16<<<dim3(32, 12), 256, 0, stream>>>(xb, Wqkvt, QKV, 4096, 1536, 1024, 1536);
  rope_rms_kernel<<<20480, 256, 0, stream>>>(QKV, cosT, sinT, Qb, Kb);
  v_transpose<<<256, 256, 0, stream>>>(QKV, Vt);
  attn_kernel<<<1024, 256, 0, stream>>>(Qb, Kb, Vt, Yb);
  gemm_bf16<<<dim3(32, 8), 256, 0, stream>>>(Yb, Wot, out, 4096, 1024, 1024, 1024);
}